// Round 5
// baseline (330.117 us; speedup 1.0000x reference)
//
#include <hip/hip_runtime.h>

// out[b,i,n] = sum_j w[i,j] * x[b,j,n]
// x: [B=256, 3, N=65536] fp32, w: [3,3] fp32, out: [B, 3, N] fp32.
// Pure streaming map: 402 MB HBM traffic, FLOPs negligible -> HBM-bound.
//
// Round-5 change: 4x fewer, 4x longer streams.
//   R4 (GRID=2048) had 2048 blocks x 6 streams (3 read + 3 write rows,
//   64 KiB apart) = ~12K concurrent DRAM streams of only 32 KiB each --
//   HBM open-row thrash is the suspected residual vs the 6.29 TB/s copy
//   ceiling (we're at ~5.7). GRID=512: each block owns 1/2 of one batch's
//   rows -> 6 streams of 128 KiB, ~3K concurrent streams total.
//   Occupancy drops to 2 wg/CU = 8 waves/CU; Little's law needs only
//   ~9.2 KB in flight per CU and we retain 8 waves x 24 loads x 1 KB,
//   so latency hiding is unaffected.
//   Kept fixed: unroll-8 body (24 independent in-flight loads), 32-bit
//   address math, nt hints, 256-thread blocks.

typedef float f32x4 __attribute__((ext_vector_type(4)));

#define B_DIM    256
#define N_DIM    65536
#define GPB      (N_DIM / 4)          // float4 groups per (b, j) row = 16384
#define BLOCK    256
#define GRID     512                  // 2 wg/CU * 256 CU
#define ITERS    32                   // 8192 groups per block / 256 threads
#define CHUNK_G  8192u                // groups per block (= GPB/2)

__global__ __launch_bounds__(BLOCK) void rot_kernel(
    const f32x4* __restrict__ x,
    const float* __restrict__ w,
    f32x4*       __restrict__ out)
{
    // 3x3 weight: wave-uniform addresses -> scalar loads, fully cached
    const float w00 = w[0], w01 = w[1], w02 = w[2];
    const float w10 = w[3], w11 = w[4], w12 = w[5];
    const float w20 = w[6], w21 = w[7], w22 = w[8];

    const unsigned bid  = blockIdx.x;           // 0..511
    const unsigned b    = bid >> 1;             // 0..255
    const unsigned half = bid & 1u;             // 0..1

    // element offset (float4 units); max < 256*49152 = 12.6M < 2^24
    unsigned base = b * (3u * GPB) + half * CHUNK_G + threadIdx.x;

    for (int ot = 0; ot < ITERS / 8; ++ot) {
#pragma unroll
        for (int it = 0; it < 8; ++it, base += BLOCK) {
            const f32x4 x0 = __builtin_nontemporal_load(x + base);
            const f32x4 x1 = __builtin_nontemporal_load(x + base + GPB);
            const f32x4 x2 = __builtin_nontemporal_load(x + base + 2u * GPB);

            f32x4 o0, o1, o2;
            o0.x = fmaf(w00, x0.x, fmaf(w01, x1.x, w02 * x2.x));
            o0.y = fmaf(w00, x0.y, fmaf(w01, x1.y, w02 * x2.y));
            o0.z = fmaf(w00, x0.z, fmaf(w01, x1.z, w02 * x2.z));
            o0.w = fmaf(w00, x0.w, fmaf(w01, x1.w, w02 * x2.w));

            o1.x = fmaf(w10, x0.x, fmaf(w11, x1.x, w12 * x2.x));
            o1.y = fmaf(w10, x0.y, fmaf(w11, x1.y, w12 * x2.y));
            o1.z = fmaf(w10, x0.z, fmaf(w11, x1.z, w12 * x2.z));
            o1.w = fmaf(w10, x0.w, fmaf(w11, x1.w, w12 * x2.w));

            o2.x = fmaf(w20, x0.x, fmaf(w21, x1.x, w22 * x2.x));
            o2.y = fmaf(w20, x0.y, fmaf(w21, x1.y, w22 * x2.y));
            o2.z = fmaf(w20, x0.z, fmaf(w21, x1.z, w22 * x2.z));
            o2.w = fmaf(w20, x0.w, fmaf(w21, x1.w, w22 * x2.w));

            __builtin_nontemporal_store(o0, out + base);
            __builtin_nontemporal_store(o1, out + base + GPB);
            __builtin_nontemporal_store(o2, out + base + 2u * GPB);
        }
    }
}

extern "C" void kernel_launch(void* const* d_in, const int* in_sizes, int n_in,
                              void* d_out, int out_size, void* d_ws, size_t ws_size,
                              hipStream_t stream)
{
    const f32x4* x = (const f32x4*)d_in[0];
    const float* w = (const float*)d_in[1];
    f32x4*       o = (f32x4*)d_out;

    rot_kernel<<<dim3(GRID), dim3(BLOCK), 0, stream>>>(x, w, o);
}